// Round 8
// baseline (122.195 us; speedup 1.0000x reference)
//
#include <hip/hip_runtime.h>

// Problem constants (from reference setup_inputs)
constexpr int Bn = 16;
constexpr int Hn = 512;
constexpr int Wn = 512;
constexpr int PADR = 15;              // 31x31 window, pad 15
constexpr float INV_KK = 1.0f / (31.0f * 31.0f);
constexpr int NBLK = 1024;            // fused grid size (64 groups x 16 batches)

// XCD-aware flat-block decode: blocks with equal (fid%8) land on the same
// XCD (dispatch round-robins). Pin batches {2x,2x+1} to XCD x so the u8
// buffer (256 KB/batch) stays L2-resident. Bijective for grids 16*G.
__device__ __forceinline__ void decode_fid(int fid, int& b, int& grp) {
    b = (fid & 7) * 2 + ((fid >> 3) & 1);
    grp = fid >> 4;
}

// ---- pass A: pack mask + horizontal 31-tap box -> combined u8 ------------
// byte = hbox(m)[0..31] | (m << 7). Also zeroes the fused-done counter.
// flat grid 1024; 4 waves; wave owns 2 rows; lane owns 8 cols.
__global__ void pack_hbox_kernel(const int* __restrict__ mask,
                                 unsigned char* __restrict__ hm8,
                                 unsigned int* __restrict__ counter) {
    if (blockIdx.x == 0 && threadIdx.x == 0) *counter = 0u;

    int b, grp;
    decode_fid(blockIdx.x, b, grp);
    const int lane = threadIdx.x & 63;
    const int wv = threadIdx.x >> 6;
    const int c0 = lane * 8;

    const int* mb = mask + (size_t)b * Hn * Wn;
    unsigned char* h8 = hm8 + (size_t)b * Hn * Wn;

#pragma unroll
    for (int rr = 0; rr < 2; ++rr) {
        const int r = grp * 8 + wv * 2 + rr;
        const int4 a = *reinterpret_cast<const int4*>(mb + (size_t)r * Wn + c0);
        const int4 c = *reinterpret_cast<const int4*>(mb + (size_t)r * Wn + c0 + 4);
        const int mv[8] = {a.x, a.y, a.z, a.w, c.x, c.y, c.z, c.w};

        unsigned int w0 = 0, w1 = 0;                   // packed mask bytes
        float q[8];
        float run = 0.0f;
#pragma unroll
        for (int k = 0; k < 8; ++k) {
            const int m = (mv[k] == 255) ? 0 : mv[k];
            if (k < 4) w0 |= (unsigned int)m << (8 * k);
            else       w1 |= (unsigned int)m << (8 * (k - 4));
            run += (float)m;
            q[k] = run;                                // in-lane inclusive
        }

        // inclusive wave scan of lane totals
        float s = q[7];
#pragma unroll
        for (int off = 1; off < 64; off <<= 1) {
            const float n = __shfl_up(s, off, 64);
            if (lane >= off) s += n;
        }
        const float pre = s - q[7];                    // exclusive prefix
        float P[8];
#pragma unroll
        for (int k = 0; k < 8; ++k) P[k] = pre + q[k];
        const float total = __shfl(P[7], 63, 64);

        // window ends: P[i-16] at (lane-2, k); P[i+15] at (lane+1, 7) for
        // k==0 else (lane+2, k-1). Clamped lanes guarded by the i-tests.
        const int sl = (lane < 2) ? 0 : lane - 2;
        const int s1 = (lane > 62) ? 63 : lane + 1;
        const int s2 = (lane > 61) ? 63 : lane + 2;
        float plo[8], phi[8];
#pragma unroll
        for (int k = 0; k < 8; ++k) plo[k] = __shfl(P[k], sl, 64);
        phi[0] = __shfl(P[7], s1, 64);
#pragma unroll
        for (int k = 1; k < 8; ++k) phi[k] = __shfl(P[k - 1], s2, 64);

        unsigned int h0w = 0, h1w = 0;
#pragma unroll
        for (int k = 0; k < 8; ++k) {
            const int i = c0 + k;
            const float lo = (i >= PADR + 1) ? plo[k] : 0.0f;
            const float hi = (i + PADR <= Wn - 1) ? phi[k] : total;
            const unsigned int hv = (unsigned int)(hi - lo);   // exact, <=31
            if (k < 4) h0w |= hv << (8 * k);
            else       h1w |= hv << (8 * (k - 4));
        }
        h0w |= (w0 & 0x01010101u) << 7;                // mask bit in bit 7
        h1w |= (w1 & 0x01010101u) << 7;
        *reinterpret_cast<uint2*>(h8 + (size_t)r * Wn + c0) = make_uint2(h0w, h1w);
    }
}

// ---- pass B: vertical slide over combined u8 + loss + last-block reduce --
// flat grid 1024; wave owns 2 rows; lane owns 8 cols. Packed-u16 vertical
// sums (hsum<=31, 31 rows -> <=961). The last block to finish reduces all
// partials and writes the final scalar (CUB-style, agent-scope acq_rel).
__global__ void fused_kernel(const float* __restrict__ pred,
                             const unsigned char* __restrict__ hm8,
                             float* __restrict__ part,
                             unsigned int* __restrict__ counter,
                             float* __restrict__ out) {
    int b, bx;
    decode_fid(blockIdx.x, b, bx);
    const int t = threadIdx.x;
    const int lane = t & 63;
    const int wv = t >> 6;
    const int r0 = bx * 8 + wv * 2;
    const int c0 = lane * 8;

    const unsigned char* hb = hm8 + (size_t)b * Hn * Wn;
    const float* pb = pred + (size_t)b * 2 * Hn * Wn;
    const float* pb1 = pb + (size_t)Hn * Wn;

    // packed u16 vertical sums of hsum (bit7 mask excluded via 0x001F001F)
    unsigned int e0 = 0, o0 = 0, e1 = 0, o1 = 0;
    {
        const int glo = (r0 - PADR < 0) ? 0 : r0 - PADR;
        const int ghi = (r0 + PADR > Hn - 1) ? Hn - 1 : r0 + PADR;
        for (int g = glo; g <= ghi; ++g) {
            const uint2 x = *reinterpret_cast<const uint2*>(hb + (size_t)g * Wn + c0);
            e0 += x.x & 0x001F001Fu; o0 += (x.x >> 8) & 0x001F001Fu;
            e1 += x.y & 0x001F001Fu; o1 += (x.y >> 8) & 0x001F001Fu;
        }
    }

    float a_weit = 0.f, a_wbce = 0.f, a_inter = 0.f, a_card = 0.f;

#pragma unroll
    for (int rr = 0; rr < 2; ++rr) {
        const int r = r0 + rr;

        const float vs[8] = {
            (float)(e0 & 0xFFFFu), (float)(o0 & 0xFFFFu),
            (float)(e0 >> 16),     (float)(o0 >> 16),
            (float)(e1 & 0xFFFFu), (float)(o1 & 0xFFFFu),
            (float)(e1 >> 16),     (float)(o1 >> 16)};

        const uint2 mm = *reinterpret_cast<const uint2*>(hb + (size_t)r * Wn + c0);
        const float4 qa0 = *reinterpret_cast<const float4*>(pb + (size_t)r * Wn + c0);
        const float4 qa1 = *reinterpret_cast<const float4*>(pb + (size_t)r * Wn + c0 + 4);
        const float4 qb0 = *reinterpret_cast<const float4*>(pb1 + (size_t)r * Wn + c0);
        const float4 qb1 = *reinterpret_cast<const float4*>(pb1 + (size_t)r * Wn + c0 + 4);
        const float pA[8] = {qa0.x, qa0.y, qa0.z, qa0.w, qa1.x, qa1.y, qa1.z, qa1.w};
        const float pB[8] = {qb0.x, qb0.y, qb0.z, qb0.w, qb1.x, qb1.y, qb1.z, qb1.w};

#pragma unroll
        for (int k = 0; k < 8; ++k) {
            const unsigned int mwrd = (k < 4) ? mm.x : mm.y;
            const int m = (mwrd >> (8 * (k & 3) + 7)) & 1;
            const float mf = (float)m;
            const float p0 = pA[k];
            const float p1 = pB[k];

            const float pooled = vs[k] * INV_KK;

            // lse = max + log(1 + exp(-|p0-p1|)): 1 exp + 1 log
            const float mx = fmaxf(p0, p1);
            const float lse = mx + __logf(1.0f + __expf(-fabsf(p0 - p1)));
            const float wbce = lse - (m ? p1 : p0);
            const float p1s = __expf(p1 - lse);

            const float weit = 1.0f + 5.0f * fabsf(pooled - mf);
            a_weit += weit;
            a_wbce += weit * wbce;
            a_inter += p1s * mf * weit;
            a_card += (p1s + mf) * weit;
        }

        if (rr == 0) {                                 // slide window 1 row
            const int ga = r + 1 + PADR;
            const int gs = r - PADR;
            if (ga < Hn) {
                const uint2 x = *reinterpret_cast<const uint2*>(hb + (size_t)ga * Wn + c0);
                e0 += x.x & 0x001F001Fu; o0 += (x.x >> 8) & 0x001F001Fu;
                e1 += x.y & 0x001F001Fu; o1 += (x.y >> 8) & 0x001F001Fu;
            }
            if (gs >= 0) {
                const uint2 x = *reinterpret_cast<const uint2*>(hb + (size_t)gs * Wn + c0);
                e0 -= x.x & 0x001F001Fu; o0 -= (x.x >> 8) & 0x001F001Fu;
                e1 -= x.y & 0x001F001Fu; o1 -= (x.y >> 8) & 0x001F001Fu;
            }
        }
    }

    // ---- block reduction: 4 waves of 64 ----
    __shared__ float red[4][4];
    __shared__ unsigned int ticket_s;
#pragma unroll
    for (int off = 32; off > 0; off >>= 1) {
        a_weit += __shfl_down(a_weit, off, 64);
        a_wbce += __shfl_down(a_wbce, off, 64);
        a_inter += __shfl_down(a_inter, off, 64);
        a_card += __shfl_down(a_card, off, 64);
    }
    if (lane == 0) {
        red[wv][0] = a_weit;
        red[wv][1] = a_wbce;
        red[wv][2] = a_inter;
        red[wv][3] = a_card;
    }
    __syncthreads();
    if (t < 4) {
        part[((size_t)b * 64 + bx) * 4 + t] =
            red[0][t] + red[1][t] + red[2][t] + red[3][t];
    }

    // ---- last-block-done reduction (device-scope handoff) ----
    __threadfence();
    if (t == 0)
        ticket_s = __hip_atomic_fetch_add(counter, 1u, __ATOMIC_ACQ_REL,
                                          __HIP_MEMORY_SCOPE_AGENT);
    __syncthreads();
    if (ticket_s == NBLK - 1) {
        __shared__ float loss[Bn];
        // wave wv reduces batches wv*4 .. wv*4+3 (64 partials each)
#pragma unroll
        for (int j = 0; j < 4; ++j) {
            const int bb = wv * 4 + j;
            const float4 v = *reinterpret_cast<const float4*>(
                part + ((size_t)bb * 64 + lane) * 4);
            float a0 = v.x, a1 = v.y, a2 = v.z, a3 = v.w;
#pragma unroll
            for (int off = 32; off > 0; off >>= 1) {
                a0 += __shfl_down(a0, off, 64);
                a1 += __shfl_down(a1, off, 64);
                a2 += __shfl_down(a2, off, 64);
                a3 += __shfl_down(a3, off, 64);
            }
            if (lane == 0) {
                const float wbce = a1 / a0;
                const float uni = a3 - a2;             // cardinality - inter
                const float wiou = 1.0f - (a2 + 1.0f) / (uni + 1.0f);
                loss[bb] = wbce + wiou;
            }
        }
        __syncthreads();
        if (t == 0) {
            float sum = 0.0f;
#pragma unroll
            for (int k = 0; k < Bn; ++k) sum += loss[k];
            out[0] = sum * (1.0f / (float)Bn);
        }
    }
}

extern "C" void kernel_launch(void* const* d_in, const int* in_sizes, int n_in,
                              void* d_out, int out_size, void* d_ws, size_t ws_size,
                              hipStream_t stream) {
    const float* pred = (const float*)d_in[0];
    const int* mask = (const int*)d_in[1];
    unsigned char* hm8 = (unsigned char*)d_ws;                   // 4 MB
    float* part = (float*)(hm8 + (size_t)Bn * Hn * Wn);          // 16 KB
    unsigned int* counter = (unsigned int*)(part + (size_t)NBLK * 4);
    float* out = (float*)d_out;

    hipLaunchKernelGGL(pack_hbox_kernel, dim3(NBLK), dim3(256), 0, stream,
                       mask, hm8, counter);
    hipLaunchKernelGGL(fused_kernel, dim3(NBLK), dim3(256), 0, stream,
                       pred, hm8, part, counter, out);
}

// Round 9
// 25.257 us; speedup vs baseline: 4.8380x; 4.8380x over previous
//
#include <hip/hip_runtime.h>

// Problem constants (from reference setup_inputs)
constexpr int Bn = 16;
constexpr int Hn = 512;
constexpr int Wn = 512;
constexpr int PADR = 15;              // 31x31 window, pad 15
constexpr float INV_KK = 1.0f / (31.0f * 31.0f);
constexpr int NBLK = 1024;            // 64 row-groups x 16 batches

// XCD-aware flat-block decode: blocks with equal (fid%8) land on the same
// XCD (dispatch round-robins). Pin batches {2x,2x+1} to XCD x so the u8
// buffer (256 KB/batch) stays L2-resident. Bijective for grids 16*G.
__device__ __forceinline__ void decode_fid(int fid, int& b, int& grp) {
    b = (fid & 7) * 2 + ((fid >> 3) & 1);
    grp = fid >> 4;
}

// ---- pass A: pack mask + horizontal 31-tap box -> combined u8 ------------
// byte = hbox(m)[0..31] | (m << 7).
// flat grid 1024; 4 waves; wave owns 2 rows; lane owns 8 cols.
__global__ void pack_hbox_kernel(const int* __restrict__ mask,
                                 unsigned char* __restrict__ hm8) {
    int b, grp;
    decode_fid(blockIdx.x, b, grp);
    const int lane = threadIdx.x & 63;
    const int wv = threadIdx.x >> 6;
    const int c0 = lane * 8;

    const int* mb = mask + (size_t)b * Hn * Wn;
    unsigned char* h8 = hm8 + (size_t)b * Hn * Wn;

#pragma unroll
    for (int rr = 0; rr < 2; ++rr) {
        const int r = grp * 8 + wv * 2 + rr;
        const int4 a = *reinterpret_cast<const int4*>(mb + (size_t)r * Wn + c0);
        const int4 c = *reinterpret_cast<const int4*>(mb + (size_t)r * Wn + c0 + 4);
        const int mv[8] = {a.x, a.y, a.z, a.w, c.x, c.y, c.z, c.w};

        unsigned int w0 = 0, w1 = 0;                   // packed mask bytes
        float q[8];
        float run = 0.0f;
#pragma unroll
        for (int k = 0; k < 8; ++k) {
            const int m = (mv[k] == 255) ? 0 : mv[k];
            if (k < 4) w0 |= (unsigned int)m << (8 * k);
            else       w1 |= (unsigned int)m << (8 * (k - 4));
            run += (float)m;
            q[k] = run;                                // in-lane inclusive
        }

        // inclusive wave scan of lane totals
        float s = q[7];
#pragma unroll
        for (int off = 1; off < 64; off <<= 1) {
            const float n = __shfl_up(s, off, 64);
            if (lane >= off) s += n;
        }
        const float pre = s - q[7];                    // exclusive prefix
        float P[8];
#pragma unroll
        for (int k = 0; k < 8; ++k) P[k] = pre + q[k];
        const float total = __shfl(P[7], 63, 64);

        // window ends: P[i-16] at (lane-2, k); P[i+15] at (lane+1, 7) for
        // k==0 else (lane+2, k-1). Clamped lanes guarded by the i-tests.
        const int sl = (lane < 2) ? 0 : lane - 2;
        const int s1 = (lane > 62) ? 63 : lane + 1;
        const int s2 = (lane > 61) ? 63 : lane + 2;
        float plo[8], phi[8];
#pragma unroll
        for (int k = 0; k < 8; ++k) plo[k] = __shfl(P[k], sl, 64);
        phi[0] = __shfl(P[7], s1, 64);
#pragma unroll
        for (int k = 1; k < 8; ++k) phi[k] = __shfl(P[k - 1], s2, 64);

        unsigned int h0w = 0, h1w = 0;
#pragma unroll
        for (int k = 0; k < 8; ++k) {
            const int i = c0 + k;
            const float lo = (i >= PADR + 1) ? plo[k] : 0.0f;
            const float hi = (i + PADR <= Wn - 1) ? phi[k] : total;
            const unsigned int hv = (unsigned int)(hi - lo);   // exact, <=31
            if (k < 4) h0w |= hv << (8 * k);
            else       h1w |= hv << (8 * (k - 4));
        }
        h0w |= (w0 & 0x01010101u) << 7;                // mask bit in bit 7
        h1w |= (w1 & 0x01010101u) << 7;
        *reinterpret_cast<uint2*>(h8 + (size_t)r * Wn + c0) = make_uint2(h0w, h1w);
    }
}

// ---- pass B: vertical slide over combined u8 + loss math -----------------
// flat grid 1024; wave owns 2 rows; lane owns 8 cols. Packed-u16 vertical
// sums (hsum<=31 per byte; 31 rows -> <=961, fits u16). Plain part stores;
// kernel boundary is the sync (no fences/atomics -- round-8 lesson).
__global__ void fused_kernel(const float* __restrict__ pred,
                             const unsigned char* __restrict__ hm8,
                             float* __restrict__ part) {
    int b, bx;
    decode_fid(blockIdx.x, b, bx);
    const int t = threadIdx.x;
    const int lane = t & 63;
    const int wv = t >> 6;
    const int r0 = bx * 8 + wv * 2;
    const int c0 = lane * 8;

    const unsigned char* hb = hm8 + (size_t)b * Hn * Wn;
    const float* pb = pred + (size_t)b * 2 * Hn * Wn;
    const float* pb1 = pb + (size_t)Hn * Wn;

    // packed u16 vertical sums of hsum (bit7 mask excluded via 0x001F001F)
    unsigned int e0 = 0, o0 = 0, e1 = 0, o1 = 0;
    {
        const int glo = (r0 - PADR < 0) ? 0 : r0 - PADR;
        const int ghi = (r0 + PADR > Hn - 1) ? Hn - 1 : r0 + PADR;
        for (int g = glo; g <= ghi; ++g) {
            const uint2 x = *reinterpret_cast<const uint2*>(hb + (size_t)g * Wn + c0);
            e0 += x.x & 0x001F001Fu; o0 += (x.x >> 8) & 0x001F001Fu;
            e1 += x.y & 0x001F001Fu; o1 += (x.y >> 8) & 0x001F001Fu;
        }
    }

    float a_weit = 0.f, a_wbce = 0.f, a_inter = 0.f, a_card = 0.f;

#pragma unroll
    for (int rr = 0; rr < 2; ++rr) {
        const int r = r0 + rr;

        const float vs[8] = {
            (float)(e0 & 0xFFFFu), (float)(o0 & 0xFFFFu),
            (float)(e0 >> 16),     (float)(o0 >> 16),
            (float)(e1 & 0xFFFFu), (float)(o1 & 0xFFFFu),
            (float)(e1 >> 16),     (float)(o1 >> 16)};

        const uint2 mm = *reinterpret_cast<const uint2*>(hb + (size_t)r * Wn + c0);
        const float4 qa0 = *reinterpret_cast<const float4*>(pb + (size_t)r * Wn + c0);
        const float4 qa1 = *reinterpret_cast<const float4*>(pb + (size_t)r * Wn + c0 + 4);
        const float4 qb0 = *reinterpret_cast<const float4*>(pb1 + (size_t)r * Wn + c0);
        const float4 qb1 = *reinterpret_cast<const float4*>(pb1 + (size_t)r * Wn + c0 + 4);
        const float pA[8] = {qa0.x, qa0.y, qa0.z, qa0.w, qa1.x, qa1.y, qa1.z, qa1.w};
        const float pB[8] = {qb0.x, qb0.y, qb0.z, qb0.w, qb1.x, qb1.y, qb1.z, qb1.w};

#pragma unroll
        for (int k = 0; k < 8; ++k) {
            const unsigned int mwrd = (k < 4) ? mm.x : mm.y;
            const int m = (mwrd >> (8 * (k & 3) + 7)) & 1;
            const float mf = (float)m;
            const float p0 = pA[k];
            const float p1 = pB[k];

            const float pooled = vs[k] * INV_KK;

            // lse = max + log(1 + exp(-|p0-p1|)): 1 exp + 1 log
            const float mx = fmaxf(p0, p1);
            const float lse = mx + __logf(1.0f + __expf(-fabsf(p0 - p1)));
            const float wbce = lse - (m ? p1 : p0);
            const float p1s = __expf(p1 - lse);

            const float weit = 1.0f + 5.0f * fabsf(pooled - mf);
            a_weit += weit;
            a_wbce += weit * wbce;
            a_inter += p1s * mf * weit;
            a_card += (p1s + mf) * weit;
        }

        if (rr == 0) {                                 // slide window 1 row
            const int ga = r + 1 + PADR;
            const int gs = r - PADR;
            if (ga < Hn) {
                const uint2 x = *reinterpret_cast<const uint2*>(hb + (size_t)ga * Wn + c0);
                e0 += x.x & 0x001F001Fu; o0 += (x.x >> 8) & 0x001F001Fu;
                e1 += x.y & 0x001F001Fu; o1 += (x.y >> 8) & 0x001F001Fu;
            }
            if (gs >= 0) {
                const uint2 x = *reinterpret_cast<const uint2*>(hb + (size_t)gs * Wn + c0);
                e0 -= x.x & 0x001F001Fu; o0 -= (x.x >> 8) & 0x001F001Fu;
                e1 -= x.y & 0x001F001Fu; o1 -= (x.y >> 8) & 0x001F001Fu;
            }
        }
    }

    // block reduction: 4 waves of 64
    __shared__ float red[4][4];
#pragma unroll
    for (int off = 32; off > 0; off >>= 1) {
        a_weit += __shfl_down(a_weit, off, 64);
        a_wbce += __shfl_down(a_wbce, off, 64);
        a_inter += __shfl_down(a_inter, off, 64);
        a_card += __shfl_down(a_card, off, 64);
    }
    if (lane == 0) {
        red[wv][0] = a_weit;
        red[wv][1] = a_wbce;
        red[wv][2] = a_inter;
        red[wv][3] = a_card;
    }
    __syncthreads();
    if (t < 4) {
        part[((size_t)b * 64 + bx) * 4 + t] =
            red[0][t] + red[1][t] + red[2][t] + red[3][t];
    }
}

// ------ single-block reduce of part[b][64][4] + per-batch loss + mean -----
__global__ void __launch_bounds__(1024)
reduce_finalize_kernel(const float* __restrict__ part, float* __restrict__ out) {
    const int t = threadIdx.x;
    const int b = t >> 6;
    const int l = t & 63;

    const float4 v = *reinterpret_cast<const float4*>(part + ((size_t)b * 64 + l) * 4);
    float a0 = v.x, a1 = v.y, a2 = v.z, a3 = v.w;
#pragma unroll
    for (int off = 32; off > 0; off >>= 1) {
        a0 += __shfl_down(a0, off, 64);
        a1 += __shfl_down(a1, off, 64);
        a2 += __shfl_down(a2, off, 64);
        a3 += __shfl_down(a3, off, 64);
    }

    __shared__ float loss[Bn];
    if (l == 0) {
        const float wbce = a1 / a0;
        const float uni = a3 - a2;                     // cardinality - inter
        const float wiou = 1.0f - (a2 + 1.0f) / (uni + 1.0f);
        loss[b] = wbce + wiou;
    }
    __syncthreads();
    if (t == 0) {
        float s = 0.0f;
#pragma unroll
        for (int k = 0; k < Bn; ++k) s += loss[k];
        out[0] = s * (1.0f / (float)Bn);
    }
}

extern "C" void kernel_launch(void* const* d_in, const int* in_sizes, int n_in,
                              void* d_out, int out_size, void* d_ws, size_t ws_size,
                              hipStream_t stream) {
    const float* pred = (const float*)d_in[0];
    const int* mask = (const int*)d_in[1];
    unsigned char* hm8 = (unsigned char*)d_ws;                   // 4 MB
    float* part = (float*)(hm8 + (size_t)Bn * Hn * Wn);          // 16 KB
    float* out = (float*)d_out;

    hipLaunchKernelGGL(pack_hbox_kernel, dim3(NBLK), dim3(256), 0, stream,
                       mask, hm8);
    hipLaunchKernelGGL(fused_kernel, dim3(NBLK), dim3(256), 0, stream,
                       pred, hm8, part);
    hipLaunchKernelGGL(reduce_finalize_kernel, dim3(1), dim3(1024), 0, stream,
                       part, out);
}